// Round 11
// baseline (1414.258 us; speedup 1.0000x reference)
//
#include <hip/hip_runtime.h>

#define NN    60000
#define NODES 100000
#define DD    64
#define NNZ   3200000
#define BB    1024
#define NEG   0.2f
#define RPB   192                        // rows per bucket: 16 waves x 12 rows exactly
#define NBUCK 521                        // ceil(NODES/RPB)
#define EPB   8192                       // edges per sort block
#define NPB   ((NNZ + EPB - 1) / EPB)    // 391
#define PLACE_T 576                      // k_place threads (>= NBUCK for its scan)
#define CAP   6912                       // bucket capacity (mean 6144, sd~78 -> +9.8s)
#define NSEG  13                         // column segments (col>>13), ~2 MB x-slice each
#define KEYN  (NSEG * RPB)               // 2496 sort keys per bucket
#define SPB   (KEYN + 1)                 // starts entries per bucket

// ---------------------------------------------------------------- init x = concat(eu, ei); also init gcur
__global__ __launch_bounds__(256) void k_init_x(const float* __restrict__ eu,
                                                const float* __restrict__ ei,
                                                float* __restrict__ x,
                                                int* __restrict__ gcur) {
    int i = blockIdx.x * 256 + threadIdx.x;          // float4 index
    if (i < NBUCK) gcur[i] = i * CAP;
    const int TOT = NODES * DD / 4;
    if (i >= TOT) return;
    const int UE = NN * DD / 4;
    float4 v = (i < UE) ? ((const float4*)eu)[i] : ((const float4*)ei)[i - UE];
    ((float4*)x)[i] = v;
}

// ---------------------------------------------------------------- bucket sort -> bulk
__global__ __launch_bounds__(PLACE_T) void k_place(const int* __restrict__ row,
                                                   const int* __restrict__ col,
                                                   const float* __restrict__ val,
                                                   int* __restrict__ gcur,
                                                   int2* __restrict__ bulk) {
    __shared__ int rows_l[EPB];                // 32 KB
    __shared__ unsigned short perm[EPB];       // 16 KB
    __shared__ int h[NBUCK], bloc[NBUCK], bcur[NBUCK], gseg[NBUCK];
    __shared__ int sc[PLACE_T];
    int t = threadIdx.x;
    if (t < NBUCK) h[t] = 0;
    __syncthreads();
    int base = blockIdx.x * EPB;
    int n = min(EPB, NNZ - base);
    for (int k = t; k < n; k += PLACE_T) {
        int r = row[base + k];
        rows_l[k] = r;
        atomicAdd(&h[r / RPB], 1);
    }
    __syncthreads();
    {
        int v = (t < NBUCK) ? h[t] : 0;
        sc[t] = v;
        __syncthreads();
        for (int off = 1; off < PLACE_T; off <<= 1) {
            int u = (t >= off) ? sc[t - off] : 0;
            __syncthreads();
            sc[t] += u;
            __syncthreads();
        }
        if (t < NBUCK) {
            int ex = sc[t] - v;
            bloc[t] = ex;
            bcur[t] = ex;
            gseg[t] = v ? atomicAdd(&gcur[t], v) : 0;
        }
    }
    __syncthreads();
    for (int k = t; k < n; k += PLACE_T) {
        int p = atomicAdd(&bcur[rows_l[k] / RPB], 1);
        perm[p] = (unsigned short)k;
    }
    __syncthreads();
    for (int j = t; j < n; j += PLACE_T) {
        int k = perm[j];
        int r = rows_l[k];
        int b = r / RPB;
        int addr = gseg[b] + (j - bloc[b]);
        bulk[addr] = make_int2(((r - b * RPB) << 17) | col[base + k],
                               __float_as_int(val[base + k]));
    }
}

// ---------------------------------------------------------------- per-bucket (colseg,row) sort
// in-place (keeps packed local-row bits); emit per-key span starts + sentinel
__global__ __launch_bounds__(512) void k_csr(const int* __restrict__ gcur,
                                             int2* __restrict__ bulk,
                                             int* __restrict__ starts) {
    __shared__ int2 eds[CAP];                  // 55.3 KB
    __shared__ int cnt[KEYN], pos[KEYN];       // 20 KB
    __shared__ int part[512];
    int b = blockIdx.x, t = threadIdx.x;
    int lo = b * CAP;
    int n = gcur[b] - lo;
    for (int k = t; k < KEYN; k += 512) cnt[k] = 0;
    __syncthreads();
    for (int i = t; i < n; i += 512) {
        int2 ed = bulk[lo + i];
        eds[i] = ed;
        int lr = ed.x >> 17, c = ed.x & 0x1FFFF;
        atomicAdd(&cnt[(c >> 13) * RPB + lr], 1);
    }
    __syncthreads();
    // two-level exclusive scan over KEYN bins (5 bins/thread)
    int run = 0;
#pragma unroll
    for (int j = 0; j < 5; ++j) {
        int k = t * 5 + j;
        if (k < KEYN) { pos[k] = run; run += cnt[k]; }
    }
    part[t] = run;
    __syncthreads();
    for (int off = 1; off < 512; off <<= 1) {
        int u = (t >= off) ? part[t - off] : 0;
        __syncthreads();
        part[t] += u;
        __syncthreads();
    }
    int poff = part[t] - run;
#pragma unroll
    for (int j = 0; j < 5; ++j) {
        int k = t * 5 + j;
        if (k < KEYN) pos[k] += poff;
    }
    __syncthreads();
    for (int k = t; k < KEYN; k += 512) {
        starts[b * SPB + k] = lo + pos[k];
        cnt[k] = pos[k];                      // reuse as cursor
    }
    if (t == 0) starts[b * SPB + KEYN] = lo + n;
    __syncthreads();
    for (int i = t; i < n; i += 512) {
        int2 ed = eds[i];
        int lr = ed.x >> 17, c = ed.x & 0x1FFFF;
        int p = atomicAdd(&cnt[(c >> 13) * RPB + lr], 1);
        bulk[lo + p] = ed;                    // keep packed (lr<<17 | col)
    }
}

// ---------------------------------------------------------------- fused convoyed SpMM + GEMM layer
// Phase S: convoyed seg-major pull SpMM into LDS acc; cv metadata scalarized via
// readfirstlane (row check = s_cmp/s_cbranch; gather base = saddr form).
// Epilogue: lane = output col; 12 rows/wave in 4 chunks of 3 with hoisted loads.
//   xout = leaky(b1+b2 + lie@W1 + (x*lie)@W2), ping-pong buffer.
__global__ __launch_bounds__(1024) void k_cspmm(const int* __restrict__ starts,
                                                const int2* __restrict__ cv,
                                                const float* __restrict__ xin,
                                                float* __restrict__ xout,
                                                const float* __restrict__ W1,
                                                const float* __restrict__ W2,
                                                const float* __restrict__ b1,
                                                const float* __restrict__ b2) {
    __shared__ float acc[RPB * DD];            // 48 KB
    int t = threadIdx.x, b = blockIdx.x;
    float4* av = (float4*)acc;
    for (int i = t; i < RPB * 16; i += 1024) av[i] = make_float4(0.f, 0.f, 0.f, 0.f);
    __syncthreads();
    const int wid = t >> 6, lane = t & 63;
    const int r0 = wid * 12;                   // exactly 12 rows per wave
    // ---------------- Phase S: SpMM ----------------
    {
        int sb = b * SPB;
        for (int seg = 0; seg < NSEG; ++seg) {
            int s = __builtin_amdgcn_readfirstlane(starts[sb + seg * RPB + r0]);
            int e = __builtin_amdgcn_readfirstlane(starts[sb + seg * RPB + r0 + 12]);
            int cur = -1;
            float f = 0.f;
            int g = s;
            for (; g + 8 <= e; g += 8) {
                int2 ee[8];
#pragma unroll
                for (int j = 0; j < 8; ++j) ee[j] = cv[g + j];
                int pk[8]; float vv[8];
#pragma unroll
                for (int j = 0; j < 8; ++j) {
                    pk[j] = __builtin_amdgcn_readfirstlane(ee[j].x);
                    vv[j] = __int_as_float(__builtin_amdgcn_readfirstlane(ee[j].y));
                }
                float xv[8];
#pragma unroll
                for (int j = 0; j < 8; ++j) xv[j] = xin[(pk[j] & 0x1FFFF) * DD + lane];
#pragma unroll
                for (int j = 0; j < 8; ++j) {
                    int r = pk[j] >> 17;
                    if (r != cur) {                 // scalar branch
                        if (cur >= 0) acc[cur * DD + lane] += f;
                        cur = r; f = 0.f;
                    }
                    f = fmaf(vv[j], xv[j], f);
                }
            }
            for (; g < e; ++g) {
                int2 ed = cv[g];
                int pk = __builtin_amdgcn_readfirstlane(ed.x);
                float v = __int_as_float(__builtin_amdgcn_readfirstlane(ed.y));
                float xg = xin[(pk & 0x1FFFF) * DD + lane];
                int r = pk >> 17;
                if (r != cur) {
                    if (cur >= 0) acc[cur * DD + lane] += f;
                    cur = r; f = 0.f;
                }
                f = fmaf(v, xg, f);
            }
            if (cur >= 0) acc[cur * DD + lane] += f;
        }
    }
    __syncthreads();
    // ---------------- epilogue GEMM ----------------
    const int row0 = b * RPB;
    const float4* xin4 = (const float4*)xin;
    float bias = b1[lane] + b2[lane];
    float o[12];
#pragma unroll
    for (int i = 0; i < 12; ++i) o[i] = bias;
    for (int k4 = 0; k4 < 16; ++k4) {
        float w1r[4], w2r[4];
#pragma unroll
        for (int kk = 0; kk < 4; ++kk) {
            w1r[kk] = W1[(k4 * 4 + kk) * DD + lane];
            w2r[kk] = W2[(k4 * 4 + kk) * DD + lane];
        }
#pragma unroll
        for (int cb = 0; cb < 4; ++cb) {
            float4 a[3], xq[3];
#pragma unroll
            for (int j = 0; j < 3; ++j) {
                int rr = r0 + cb * 3 + j;
                a[j] = av[rr * 16 + k4];                        // LDS broadcast
                int gr = row0 + rr;
                xq[j] = (gr < NODES) ? xin4[gr * 16 + k4]
                                     : make_float4(0.f, 0.f, 0.f, 0.f);
            }
#pragma unroll
            for (int j = 0; j < 3; ++j) {
                float oi = o[cb * 3 + j];
                oi = fmaf(a[j].x, w1r[0], oi);
                oi = fmaf(a[j].y, w1r[1], oi);
                oi = fmaf(a[j].z, w1r[2], oi);
                oi = fmaf(a[j].w, w1r[3], oi);
                oi = fmaf(a[j].x * xq[j].x, w2r[0], oi);
                oi = fmaf(a[j].y * xq[j].y, w2r[1], oi);
                oi = fmaf(a[j].z * xq[j].z, w2r[2], oi);
                oi = fmaf(a[j].w * xq[j].w, w2r[3], oi);
                o[cb * 3 + j] = oi;
            }
        }
    }
#pragma unroll
    for (int i = 0; i < 12; ++i) {
        int gr = row0 + r0 + i;
        if (gr < NODES) {
            float v = o[i];
            xout[gr * DD + lane] = v >= 0.f ? v : NEG * v;
        }
    }
}

// ---------------------------------------------------------------- gather layer repr into output
__global__ __launch_bounds__(256) void k_gather(const float* __restrict__ x,
                                                const int* __restrict__ su,
                                                const int* __restrict__ oi,
                                                const int* __restrict__ ui,
                                                float* __restrict__ out, int layer) {
    int w    = (blockIdx.x * 256 + threadIdx.x) >> 6;
    int lane = threadIdx.x & 63;
    if (w >= 3 * BB) return;
    int g = w >> 10, b = w & 1023;
    int node = (g == 0) ? su[b] : (NN + ((g == 1) ? oi[b] : ui[b]));
    out[w * 256 + layer * 64 + lane] = x[node * DD + lane];
}

// ---------------------------------------------------------------- launch
extern "C" void kernel_launch(void* const* d_in, const int* in_sizes, int n_in,
                              void* d_out, int out_size, void* d_ws, size_t ws_size,
                              hipStream_t stream) {
    const int*   edge_row = (const int*)d_in[0];
    const int*   edge_col = (const int*)d_in[1];
    const float* edge_val = (const float*)d_in[2];
    const float* eu = (const float*)d_in[3];
    const float* ei = (const float*)d_in[4];
    const float* W1 = (const float*)d_in[5];
    const float* W2 = (const float*)d_in[6];
    const float* b1 = (const float*)d_in[7];
    const float* b2 = (const float*)d_in[8];
    const int*   su = (const int*)d_in[9];
    const int*   oi = (const int*)d_in[10];
    const int*   ui = (const int*)d_in[11];
    float* out = (float*)d_out;

    // workspace carve (~85 MB)
    float* xA     = (float*)d_ws;                    // 25.6 MB
    float* xB     = xA + NODES * DD;                 // 25.6 MB (ping-pong)
    int2*  bulk   = (int2*)(xB + NODES * DD);        // NBUCK*CAP int2 (28.8 MB)
    int*   gcur   = (int*)(bulk + NBUCK * CAP);      // NBUCK
    int*   starts = gcur + NBUCK + 1;                // NBUCK*SPB (5.2 MB)

    k_init_x<<<(NODES * DD / 4 + 255) / 256, 256, 0, stream>>>(eu, ei, xA, gcur);
    k_gather<<<(3 * BB * 64 + 255) / 256, 256, 0, stream>>>(xA, su, oi, ui, out, 0);

    k_place<<<NPB, PLACE_T, 0, stream>>>(edge_row, edge_col, edge_val, gcur, bulk);
    k_csr<<<NBUCK, 512, 0, stream>>>(gcur, bulk, starts);

    const float* xi = xA;
    float*       xo = xB;
    for (int l = 0; l < 3; ++l) {
        k_cspmm<<<NBUCK, 1024, 0, stream>>>(starts, bulk, xi, xo,
                                            W1 + l * 4096, W2 + l * 4096,
                                            b1 + l * 64,  b2 + l * 64);
        k_gather<<<(3 * BB * 64 + 255) / 256, 256, 0, stream>>>(xo, su, oi, ui, out, l + 1);
        const float* tmp = xo; xo = (float*)xi; xi = tmp;
    }
}

// Round 12
// 595.084 us; speedup vs baseline: 2.3766x; 2.3766x over previous
//
#include <hip/hip_runtime.h>

#define NN    60000
#define NODES 100000
#define DD    64
#define NNZ   3200000
#define BB    1024
#define NEG   0.2f
#define RPB   256                        // rows per bucket
#define NBUCK 391                        // ceil(NODES/RPB)
#define EPB   8192                       // edges per sort block
#define NPB   ((NNZ + EPB - 1) / EPB)    // 391
#define CAP   8960                       // bucket capacity (mean 8184, sd~90)

// ---------------------------------------------------------------- init x = concat(eu, ei); also init gcur
__global__ __launch_bounds__(256) void k_init_x(const float* __restrict__ eu,
                                                const float* __restrict__ ei,
                                                float* __restrict__ x,
                                                int* __restrict__ gcur) {
    int i = blockIdx.x * 256 + threadIdx.x;          // float4 index
    if (i < NBUCK) gcur[i] = i * CAP;
    const int TOT = NODES * DD / 4;
    if (i >= TOT) return;
    const int UE = NN * DD / 4;
    float4 v = (i < UE) ? ((const float4*)eu)[i] : ((const float4*)ei)[i - UE];
    ((float4*)x)[i] = v;
}

// ---------------------------------------------------------------- bucket sort -> bulk
// block-local LDS counting sort -> contiguous ascending global write runs
__global__ __launch_bounds__(512) void k_place(const int* __restrict__ row,
                                               const int* __restrict__ col,
                                               const float* __restrict__ val,
                                               int* __restrict__ gcur,
                                               int2* __restrict__ bulk) {
    __shared__ int rows_l[EPB];                // 32 KB
    __shared__ unsigned short perm[EPB];       // 16 KB
    __shared__ int h[NBUCK], bloc[NBUCK], bcur[NBUCK], gseg[NBUCK];
    __shared__ int sc[512];
    int t = threadIdx.x;
    if (t < NBUCK) h[t] = 0;
    __syncthreads();
    int base = blockIdx.x * EPB;
    int n = min(EPB, NNZ - base);
    for (int k = t; k < n; k += 512) {
        int r = row[base + k];
        rows_l[k] = r;
        atomicAdd(&h[r >> 8], 1);
    }
    __syncthreads();
    {
        int v = (t < NBUCK) ? h[t] : 0;
        sc[t] = v;
        __syncthreads();
        for (int off = 1; off < 512; off <<= 1) {
            int u = (t >= off) ? sc[t - off] : 0;
            __syncthreads();
            sc[t] += u;
            __syncthreads();
        }
        if (t < NBUCK) {
            int ex = sc[t] - v;
            bloc[t] = ex;
            bcur[t] = ex;
            gseg[t] = v ? atomicAdd(&gcur[t], v) : 0;
        }
    }
    __syncthreads();
    for (int k = t; k < n; k += 512) {
        int p = atomicAdd(&bcur[rows_l[k] >> 8], 1);
        perm[p] = (unsigned short)k;
    }
    __syncthreads();
    for (int j = t; j < n; j += 512) {
        int k = perm[j];
        int r = rows_l[k];
        int b8 = r >> 8;
        int addr = gseg[b8] + (j - bloc[b8]);
        bulk[addr] = make_int2(((r & 255) << 17) | col[base + k],
                               __float_as_int(val[base + k]));
    }
}

// ---------------------------------------------------------------- per-bucket row sort (in place)
// 256-bin counting sort; emits per-row (start,end) spans into rsd
__global__ __launch_bounds__(512) void k_csr(const int* __restrict__ gcur,
                                             int2* __restrict__ bulk,
                                             int2* __restrict__ rsd) {
    __shared__ int2 eds[CAP];                  // 71.7 KB
    __shared__ int cnt[RPB], cur[RPB];
    __shared__ int part[512];
    int b = blockIdx.x, t = threadIdx.x;
    int lo = b * CAP;
    int n = gcur[b] - lo;
    if (t < RPB) cnt[t] = 0;
    __syncthreads();
    for (int i = t; i < n; i += 512) {
        int2 ed = bulk[lo + i];
        eds[i] = ed;
        atomicAdd(&cnt[ed.x >> 17], 1);
    }
    __syncthreads();
    int v = (t < RPB) ? cnt[t] : 0;
    part[t] = v;
    __syncthreads();
    for (int off = 1; off < 512; off <<= 1) {
        int u = (t >= off) ? part[t - off] : 0;
        __syncthreads();
        part[t] += u;
        __syncthreads();
    }
    if (t < RPB) {
        int ex = part[t] - v;
        cur[t] = ex;
        int r = b * RPB + t;
        if (r < NODES) rsd[r] = make_int2(lo + ex, lo + ex + v);
    }
    __syncthreads();
    for (int i = t; i < n; i += 512) {
        int2 ed = eds[i];
        int p = atomicAdd(&cur[ed.x >> 17], 1);
        bulk[lo + p] = make_int2(ed.x & 0x1FFFF, ed.y);
    }
}

// ---------------------------------------------------------------- pull SpMM, float4 gathers:
// one wave / row; lane = 16*edge_slot + dim_quad; one dwordx4 gather serves 4 edges
// (4x fewer gather instructions than scalar-gather variants).
__global__ __launch_bounds__(256) void k_spmm(const int2* __restrict__ rsd,
                                              const int2* __restrict__ cv,
                                              const float* __restrict__ x,
                                              float* __restrict__ lie) {
    int w    = (blockIdx.x * 256 + threadIdx.x) >> 6;
    int lane = threadIdx.x & 63;
    if (w >= NODES) return;
    int2 se = rsd[w];
    int s = se.x, e = se.y;
    int eg = lane >> 4;          // edge slot 0..3
    int d4 = lane & 15;          // dim quad 0..15
    float4 f = make_float4(0.f, 0.f, 0.f, 0.f);
    int g = s;
    for (; g + 16 <= e; g += 16) {           // 16 edges, 4 gathers in flight
        int2 e0 = cv[g + eg];
        int2 e1 = cv[g + 4 + eg];
        int2 e2 = cv[g + 8 + eg];
        int2 e3 = cv[g + 12 + eg];
        float4 x0 = *(const float4*)&x[e0.x * DD + d4 * 4];
        float4 x1 = *(const float4*)&x[e1.x * DD + d4 * 4];
        float4 x2 = *(const float4*)&x[e2.x * DD + d4 * 4];
        float4 x3 = *(const float4*)&x[e3.x * DD + d4 * 4];
        float v0 = __int_as_float(e0.y), v1 = __int_as_float(e1.y);
        float v2 = __int_as_float(e2.y), v3 = __int_as_float(e3.y);
        f.x = fmaf(v0, x0.x, f.x); f.y = fmaf(v0, x0.y, f.y);
        f.z = fmaf(v0, x0.z, f.z); f.w = fmaf(v0, x0.w, f.w);
        f.x = fmaf(v1, x1.x, f.x); f.y = fmaf(v1, x1.y, f.y);
        f.z = fmaf(v1, x1.z, f.z); f.w = fmaf(v1, x1.w, f.w);
        f.x = fmaf(v2, x2.x, f.x); f.y = fmaf(v2, x2.y, f.y);
        f.z = fmaf(v2, x2.z, f.z); f.w = fmaf(v2, x2.w, f.w);
        f.x = fmaf(v3, x3.x, f.x); f.y = fmaf(v3, x3.y, f.y);
        f.z = fmaf(v3, x3.z, f.z); f.w = fmaf(v3, x3.w, f.w);
    }
    for (; g < e; g += 4) {                  // tail: 4 edges, clamped
        int ei = g + eg;
        int2 ed = cv[min(ei, e - 1)];
        float v = (ei < e) ? __int_as_float(ed.y) : 0.f;
        float4 xv = *(const float4*)&x[ed.x * DD + d4 * 4];
        f.x = fmaf(v, xv.x, f.x); f.y = fmaf(v, xv.y, f.y);
        f.z = fmaf(v, xv.z, f.z); f.w = fmaf(v, xv.w, f.w);
    }
    // reduce over edge slots: lanes L, L^16, L^32, L^48 hold the same dims
    f.x += __shfl_xor(f.x, 16); f.y += __shfl_xor(f.y, 16);
    f.z += __shfl_xor(f.z, 16); f.w += __shfl_xor(f.w, 16);
    f.x += __shfl_xor(f.x, 32); f.y += __shfl_xor(f.y, 32);
    f.z += __shfl_xor(f.z, 32); f.w += __shfl_xor(f.w, 32);
    if (lane < 16) *(float4*)&lie[w * DD + lane * 4] = f;
}

// ---------------------------------------------------------------- fused layer GEMM (proven R8 form)
__global__ __launch_bounds__(256) void k_gemm(float* __restrict__ x,
                                              const float* __restrict__ lie,
                                              const float* __restrict__ W1,
                                              const float* __restrict__ W2,
                                              const float* __restrict__ b1,
                                              const float* __restrict__ b2) {
    __shared__ float A1[64 * 64];
    __shared__ float A2[64 * 64];
    __shared__ float Ws1[64 * 64];
    __shared__ float Ws2[64 * 64];

    const int t = threadIdx.x;
    const int row0 = blockIdx.x * 64;

    {
        const float4* w1v = (const float4*)W1;
        const float4* w2v = (const float4*)W2;
        float4* s1v = (float4*)Ws1;
        float4* s2v = (float4*)Ws2;
#pragma unroll
        for (int q = 0; q < 4; ++q) {
            s1v[q * 256 + t] = w1v[q * 256 + t];
            s2v[q * 256 + t] = w2v[q * 256 + t];
        }
    }
#pragma unroll
    for (int q = 0; q < 4; ++q) {
        int f4 = q * 256 + t;
        int rl = f4 >> 4;
        int c4 = f4 & 15;
        int gr = row0 + rl;
        float4 lv = make_float4(0.f, 0.f, 0.f, 0.f);
        float4 xv = make_float4(0.f, 0.f, 0.f, 0.f);
        if (gr < NODES) {
            lv = *(const float4*)&lie[gr * DD + c4 * 4];
            xv = *(const float4*)&x[gr * DD + c4 * 4];
        }
        int sg = c4 ^ (rl & 15);
        ((float4*)A1)[rl * 16 + sg] = lv;
        ((float4*)A2)[rl * 16 + sg] = make_float4(lv.x * xv.x, lv.y * xv.y,
                                                  lv.z * xv.z, lv.w * xv.w);
    }
    __syncthreads();

    const int tx = t & 15;
    const int ty = t >> 4;
    float bs[4];
    {
        float4 bb1 = *(const float4*)&b1[tx * 4];
        float4 bb2 = *(const float4*)&b2[tx * 4];
        bs[0] = bb1.x + bb2.x; bs[1] = bb1.y + bb2.y;
        bs[2] = bb1.z + bb2.z; bs[3] = bb1.w + bb2.w;
    }
    float acc[4][4];
#pragma unroll
    for (int i = 0; i < 4; ++i)
#pragma unroll
        for (int j = 0; j < 4; ++j) acc[i][j] = bs[j];

    for (int k4 = 0; k4 < 16; ++k4) {
        float4 a1[4], a2[4];
#pragma unroll
        for (int i = 0; i < 4; ++i) {
            int r = ty * 4 + i;
            int sg = k4 ^ (r & 15);
            a1[i] = ((const float4*)A1)[r * 16 + sg];
            a2[i] = ((const float4*)A2)[r * 16 + sg];
        }
#pragma unroll
        for (int kk = 0; kk < 4; ++kk) {
            float4 w1 = ((const float4*)Ws1)[(k4 * 4 + kk) * 16 + tx];
            float4 w2 = ((const float4*)Ws2)[(k4 * 4 + kk) * 16 + tx];
#pragma unroll
            for (int i = 0; i < 4; ++i) {
                float av1 = (&a1[i].x)[kk];
                float av2 = (&a2[i].x)[kk];
                acc[i][0] = fmaf(av1, w1.x, fmaf(av2, w2.x, acc[i][0]));
                acc[i][1] = fmaf(av1, w1.y, fmaf(av2, w2.y, acc[i][1]));
                acc[i][2] = fmaf(av1, w1.z, fmaf(av2, w2.z, acc[i][2]));
                acc[i][3] = fmaf(av1, w1.w, fmaf(av2, w2.w, acc[i][3]));
            }
        }
    }
#pragma unroll
    for (int i = 0; i < 4; ++i) {
        int gr = row0 + ty * 4 + i;
        if (gr < NODES) {
            float4 o;
            o.x = acc[i][0] >= 0.f ? acc[i][0] : NEG * acc[i][0];
            o.y = acc[i][1] >= 0.f ? acc[i][1] : NEG * acc[i][1];
            o.z = acc[i][2] >= 0.f ? acc[i][2] : NEG * acc[i][2];
            o.w = acc[i][3] >= 0.f ? acc[i][3] : NEG * acc[i][3];
            *(float4*)&x[gr * DD + tx * 4] = o;
        }
    }
}

// ---------------------------------------------------------------- gather layer repr into output
__global__ __launch_bounds__(256) void k_gather(const float* __restrict__ x,
                                                const int* __restrict__ su,
                                                const int* __restrict__ oi,
                                                const int* __restrict__ ui,
                                                float* __restrict__ out, int layer) {
    int w    = (blockIdx.x * 256 + threadIdx.x) >> 6;
    int lane = threadIdx.x & 63;
    if (w >= 3 * BB) return;
    int g = w >> 10, b = w & 1023;
    int node = (g == 0) ? su[b] : (NN + ((g == 1) ? oi[b] : ui[b]));
    out[w * 256 + layer * 64 + lane] = x[node * DD + lane];
}

// ---------------------------------------------------------------- launch
extern "C" void kernel_launch(void* const* d_in, const int* in_sizes, int n_in,
                              void* d_out, int out_size, void* d_ws, size_t ws_size,
                              hipStream_t stream) {
    const int*   edge_row = (const int*)d_in[0];
    const int*   edge_col = (const int*)d_in[1];
    const float* edge_val = (const float*)d_in[2];
    const float* eu = (const float*)d_in[3];
    const float* ei = (const float*)d_in[4];
    const float* W1 = (const float*)d_in[5];
    const float* W2 = (const float*)d_in[6];
    const float* b1 = (const float*)d_in[7];
    const float* b2 = (const float*)d_in[8];
    const int*   su = (const int*)d_in[9];
    const int*   oi = (const int*)d_in[10];
    const int*   ui = (const int*)d_in[11];
    float* out = (float*)d_out;

    // workspace carve (~80 MB)
    float* x    = (float*)d_ws;                    // 25.6 MB
    float* lie  = x + NODES * DD;                  // 25.6 MB
    int2*  bulk = (int2*)(lie + NODES * DD);       // NBUCK*CAP int2 (28 MB)
    int*   gcur = (int*)(bulk + NBUCK * CAP);      // NBUCK
    int2*  rsd  = (int2*)(gcur + NBUCK + 1);       // NODES int2 (800 KB)

    k_init_x<<<(NODES * DD / 4 + 255) / 256, 256, 0, stream>>>(eu, ei, x, gcur);
    k_gather<<<(3 * BB * 64 + 255) / 256, 256, 0, stream>>>(x, su, oi, ui, out, 0);

    k_place<<<NPB, 512, 0, stream>>>(edge_row, edge_col, edge_val, gcur, bulk);
    k_csr<<<NBUCK, 512, 0, stream>>>(gcur, bulk, rsd);

    for (int l = 0; l < 3; ++l) {
        k_spmm<<<(NODES * 64 + 255) / 256, 256, 0, stream>>>(rsd, bulk, x, lie);
        k_gemm<<<(NODES + 63) / 64, 256, 0, stream>>>(x, lie,
                                                      W1 + l * 4096, W2 + l * 4096,
                                                      b1 + l * 64,  b2 + l * 64);
        k_gather<<<(3 * BB * 64 + 255) / 256, 256, 0, stream>>>(x, su, oi, ui, out, l + 1);
    }
}